// Round 9
// baseline (681.695 us; speedup 1.0000x reference)
//
#include <hip/hip_runtime.h>

// EquiConv fully-fused pipeline (round 10): MFMA split-bf16, cvt_pk staging.
// E = 200000, MUL_S = 128, MUL_V = 64, FC_IN = 128, FC_HID = 64, LEN_W = 192.
//
// Identical structure to round 9 (all six matmuls on 16x16x32 bf16 MFMA,
// hi+lo split = 3 K-passes, fragment-ordered weights, LDS-bounced vec store).
// Changes:
//   1. All activation hi/lo splits use v_cvt_pk_bf16_f32 (gfx950 packed
//      RTNE converter, inline asm -- no builtin): ~3 VALU ops/float vs ~10
//      for the manual round-to-nearest bit trick. Cuts staging VALU ~3x and
//      shrinks live temps at the 128-reg cap (round-9 counters showed ~10
//      dwords/thread of residual spill: WRITE 325 MB vs 256 MB output).
//   2. Split stores vectorized (uint2 / uint4 LDS writes).
//   3. s_setprio(1) around MFMA clusters (T5: co-resident blocks at
//      different phases -> scheduler can prefer the MFMA-issuing wave).
//
// MFMA layouts (gfx950, verified rounds 6-9):
//   A-frag: lane holds A[row = l&15][k = 32*ks + 8*(l>>4) + j]
//   B-frag: lane holds B[k][col = l&15] from fragment-ordered storage
//   C/D  : col = l&15, row = 4*(l>>4) + reg
//
// ws (u16): WB 0 (65536) | W0 65536 (16384) | W1 81920 (8192)
//           W2 90112 (24576) | WP3 114688 (8192) | WD 122880 (24576)

typedef short bf16x8 __attribute__((ext_vector_type(8)));
typedef float f32x4 __attribute__((ext_vector_type(4)));
typedef unsigned short u16;

#define MFMA16(a, b, c) __builtin_amdgcn_mfma_f32_16x16x32_bf16((a), (b), (c), 0, 0, 0)

__device__ __forceinline__ u16 f2bf(float x) {
    unsigned u = __float_as_uint(x);
    u += 0x7FFFu + ((u >> 16) & 1u);
    return (u16)(u >> 16);
}
__device__ __forceinline__ float bf2f(u16 h) {
    return __uint_as_float(((unsigned)h) << 16);
}
__device__ __forceinline__ float sigmoidf_(float x) { return 1.0f / (1.0f + __expf(-x)); }

// packed f32x2 -> bf16x2 (RTNE), gfx950 instruction; dst.lo = bf16(a), dst.hi = bf16(b)
__device__ __forceinline__ unsigned cvt_pk_bf16(float a, float b) {
    unsigned r;
    asm("v_cvt_pk_bf16_f32 %0, %1, %2" : "=v"(r) : "v"(a), "v"(b));
    return r;
}
// 2-value hi/lo split: .x = packed hi pair, .y = packed lo pair
__device__ __forceinline__ uint2 split_pk(float a, float b) {
    unsigned h = cvt_pk_bf16(a, b);
    float fa = __uint_as_float(h << 16);
    float fb = __uint_as_float(h & 0xffff0000u);
    unsigned lo = cvt_pk_bf16(a - fa, b - fb);
    return make_uint2(h, lo);
}

__device__ __forceinline__ void split_wr(u16* hip, u16* lop, float4 v) {
    uint2 p01 = split_pk(v.x, v.y);
    uint2 p23 = split_pk(v.z, v.w);
    *(uint2*)hip = make_uint2(p01.x, p23.x);
    *(uint2*)lop = make_uint2(p01.y, p23.y);
}

// ---------------------------------------------------------------- prep
// Fragment-ordered split weights: flat = ((nt*KB2 + kb)*64 + lane)*8 + j;
// n = 16*nt + (lane&15); k = 32*(kb mod KS) + 8*(lane>>4) + j; kb<KS -> hi.
__global__ __launch_bounds__(256) void prep_weights(
    const float* __restrict__ w1_p0, const float* __restrict__ w2_p0,
    const float* __restrict__ w1_p1, const float* __restrict__ w2_p1,
    const float* __restrict__ w1_p2, const float* __restrict__ w2_p2,
    const float* __restrict__ w1_p3, const float* __restrict__ w2_p3,
    const float* __restrict__ w1_p4, const float* __restrict__ w2_p4,
    const float* __restrict__ w1_p5, const float* __restrict__ w2_p5,
    const float* __restrict__ fc_w0, const float* __restrict__ fc_w1,
    const float* __restrict__ fc_w2,
    u16* __restrict__ W)
{
    const float INV_S = 0.08838834764831845f;   // 1/sqrt(128)
    const float INV_V = 0.125f;                 // 1/sqrt(64)
    const float SQ2   = 0.7071067811865476f;
    const float SQ3   = 0.5773502691896258f;
    int gid = blockIdx.x * 256 + threadIdx.x;
    if (gid >= 147456) return;
    float w = 0.f;
    int islo = 0;
    if (gid < 65536) {                       // WB: N=256 K=128 (Wbig)
        int g = gid, j = g & 7, ll = (g >> 3) & 63, rest = g >> 9;
        int kb = rest & 7, nt = rest >> 3;
        int n = nt * 16 + (ll & 15);
        islo = (kb >= 4);
        int k = 32 * (kb & 3) + 8 * (ll >> 4) + j;
        if (n < 128)      w = w1_p0[k * 128 + n] * w2_p0[n];
        else if (n < 192) w = w1_p1[k * 64 + (n - 128)] * w2_p1[n - 128];
        else              w = w1_p2[k * 64 + (n - 192)] * w2_p2[n - 192];
        w *= (INV_S * SQ2);
    } else if (gid < 81920) {                // W0: N=64 K=128
        int g = gid - 65536, j = g & 7, ll = (g >> 3) & 63, rest = g >> 9;
        int kb = rest & 7, nt = rest >> 3;
        int n = nt * 16 + (ll & 15);
        islo = (kb >= 4);
        int k = 32 * (kb & 3) + 8 * (ll >> 4) + j;
        w = fc_w0[k * 64 + n];
    } else if (gid < 90112) {                // W1: N=64 K=64
        int g = gid - 81920, j = g & 7, ll = (g >> 3) & 63, rest = g >> 9;
        int kb = rest & 3, nt = rest >> 2;
        int n = nt * 16 + (ll & 15);
        islo = (kb >= 2);
        int k = 32 * (kb & 1) + 8 * (ll >> 4) + j;
        w = fc_w1[k * 64 + n];
    } else if (gid < 114688) {               // W2: N=192 K=64
        int g = gid - 90112, j = g & 7, ll = (g >> 3) & 63, rest = g >> 9;
        int kb = rest & 3, nt = rest >> 2;
        int n = nt * 16 + (ll & 15);
        islo = (kb >= 2);
        int k = 32 * (kb & 1) + 8 * (ll >> 4) + j;
        w = fc_w2[k * 192 + n];
    } else if (gid < 122880) {               // WP3: N=64(w) K=64(u), w1_p3 scaled
        int g = gid - 114688, j = g & 7, ll = (g >> 3) & 63, rest = g >> 9;
        int kb = rest & 3, nt = rest >> 2;
        int n = nt * 16 + (ll & 15);
        islo = (kb >= 2);
        int k = 32 * (kb & 1) + 8 * (ll >> 4) + j;
        w = w1_p3[k * 64 + n] * w2_p3[n] * (INV_V * SQ2);
    } else {                                 // WD: N=192 K=64 (Wd)
        int g = gid - 122880, j = g & 7, ll = (g >> 3) & 63, rest = g >> 9;
        int kb = rest & 3, nt = rest >> 2;
        int n = nt * 16 + (ll & 15);
        islo = (kb >= 2);
        int k = 32 * (kb & 1) + 8 * (ll >> 4) + j;
        w = (n < 128 ? w1_p4[k * 128 + n] * w2_p4[n]
                     : w1_p5[k * 64 + (n - 128)] * w2_p5[n - 128]) * (INV_V * SQ3 * SQ2);
    }
    u16 h = f2bf(w);
    W[gid] = islo ? f2bf(w - bf2f(h)) : h;
}

// ---------------------------------------------------------------- fused
__global__ __launch_bounds__(256, 4) void fused_kernel(
    const float* __restrict__ fea_in1, const float* __restrict__ fea_in2,
    const float* __restrict__ fea_w,
    const float* __restrict__ fc_b0, const float* __restrict__ fc_b1,
    const float* __restrict__ fc_b2,
    const u16* __restrict__ Wg,
    float* __restrict__ out)
{
    __shared__ __align__(16) u16 SM[13312];      // 26624 B
    u16* B1 = SM;                 // 8704: x1s/fw [32][272]; xv bufs 2x[32][136]
    u16* B2 = SM + 8704;          // 4352: h0/h1/d [32][136]
    float* X2 = (float*)(SM + 13056);  // [4][32] (bytes 26112.. -- outside bounce)
    float* OB = (float*)SM;       // vec-out bounce [32][196] floats (25088 B)

    const int t   = threadIdx.x;
    const int l   = t & 63;
    const int cw  = t >> 6;       // wave id 0..3 (column wave)
    const int lm  = l & 15;
    const int lk  = l >> 4;
    const int lk8 = lk * 8;
    const long e0b = (long)blockIdx.x * 32;

    // ---- P1: stage x2 (transposed) + split x1s
    if (t < 32) {
        float4 v = *(const float4*)(fea_in2 + (e0b + t) * 4);
        X2[t] = v.x; X2[32 + t] = v.y; X2[64 + t] = v.z; X2[96 + t] = v.w;
    }
    #pragma unroll
    for (int r = 0; r < 4; ++r) {
        int f = t + r * 256, ee = f >> 5, c4 = f & 31;
        float4 v = *(const float4*)(fea_in1 + (e0b + ee) * 320 + c4 * 4);
        split_wr(&B1[ee * 272 + c4 * 4], &B1[ee * 272 + 128 + c4 * 4], v);
    }
    __syncthreads();

    // ---- P2: S1 = x1s @ Wbig -> scal(2 tiles) gate(1) vcoef(1); 96 MFMA
    f32x4 aS1[4][2] = {};
    {
        const int ctn[4] = {2 * cw, 2 * cw + 1, 8 + cw, 12 + cw};
        const u16* bp[4];
        #pragma unroll
        for (int c = 0; c < 4; ++c) bp[c] = Wg + (ctn[c] * 8) * 512 + l * 8;
        const u16* a0p = B1 + lm * 272 + lk8;
        const u16* a1p = B1 + (16 + lm) * 272 + lk8;
        __builtin_amdgcn_s_setprio(1);
        #pragma unroll 1
        for (int pass = 0; pass < 3; ++pass) {
            const int ao  = (pass == 1) ? 128 : 0;
            const int kb0 = (pass == 2) ? 4 : 0;
            #pragma unroll
            for (int ks = 0; ks < 4; ++ks) {
                bf16x8 a0 = *(const bf16x8*)(a0p + ao + 32 * ks);
                bf16x8 a1 = *(const bf16x8*)(a1p + ao + 32 * ks);
                #pragma unroll
                for (int c = 0; c < 4; ++c) {
                    bf16x8 b = *(const bf16x8*)(bp[c] + (kb0 + ks) * 512);
                    aS1[c][0] = MFMA16(a0, b, aS1[c][0]);
                    aS1[c][1] = MFMA16(a1, b, aS1[c][1]);
                }
            }
        }
        __builtin_amdgcn_s_setprio(0);
    }
    // fold x2s into scal+gate tiles (NOT vcoef)
    #pragma unroll
    for (int m = 0; m < 2; ++m)
        #pragma unroll
        for (int r = 0; r < 4; ++r) {
            float xs = X2[16 * m + 4 * lk + r];
            aS1[0][m][r] *= xs;
            aS1[1][m][r] *= xs;
            aS1[2][m][r] *= xs;
        }
    __syncthreads();                          // x1s reads done

    // ---- P3: stage fw over B1; d[e][u] from fp32 global xv (8 regs)
    #pragma unroll
    for (int r = 0; r < 4; ++r) {
        int f = t + r * 256, ee = f >> 5, c4 = f & 31;
        float4 v = *(const float4*)(fea_w + (e0b + ee) * 128 + c4 * 4);
        split_wr(&B1[ee * 272 + c4 * 4], &B1[ee * 272 + 128 + c4 * 4], v);
    }
    float d8[8];
    {
        int de = t & 31, u0 = 8 * (t >> 5);
        const float* p = fea_in1 + (e0b + de) * 320 + 128 + 3 * u0;
        float4 qa = *(const float4*)(p +  0), qb = *(const float4*)(p +  4);
        float4 qc = *(const float4*)(p +  8), qd = *(const float4*)(p + 12);
        float4 qe = *(const float4*)(p + 16), qf = *(const float4*)(p + 20);
        float c1 = X2[32 + de], c2 = X2[64 + de], c3 = X2[96 + de];
        d8[0] = qa.x * c1 + qa.y * c2 + qa.z * c3;
        d8[1] = qa.w * c1 + qb.x * c2 + qb.y * c3;
        d8[2] = qb.z * c1 + qb.w * c2 + qc.x * c3;
        d8[3] = qc.y * c1 + qc.z * c2 + qc.w * c3;
        d8[4] = qd.x * c1 + qd.y * c2 + qd.z * c3;
        d8[5] = qd.w * c1 + qe.x * c2 + qe.y * c3;
        d8[6] = qe.z * c1 + qe.w * c2 + qf.x * c3;
        d8[7] = qf.y * c1 + qf.z * c2 + qf.w * c3;
    }
    __syncthreads();

    // xv i-tile stager: 32 rows x 64 u, stride-12B gather (L1/L2-hot after P3)
    auto stage_xv = [&](int i, u16* buf) {
        int ee = t >> 3, u0 = 8 * (t & 7);
        const float* p = fea_in1 + (e0b + ee) * 320 + 128 + i + 3 * u0;
        float v[8];
        #pragma unroll
        for (int q = 0; q < 8; ++q) v[q] = p[3 * q];
        unsigned hv[4], lv[4];
        #pragma unroll
        for (int q = 0; q < 4; ++q) {
            uint2 pr = split_pk(v[2 * q], v[2 * q + 1]);
            hv[q] = pr.x; lv[q] = pr.y;
        }
        *(uint4*)&buf[ee * 136 + u0]      = make_uint4(hv[0], hv[1], hv[2], hv[3]);
        *(uint4*)&buf[ee * 136 + 64 + u0] = make_uint4(lv[0], lv[1], lv[2], lv[3]);
    };

    // column-strided split writer for h0/h1 (values at e = e0+0..3, col kc)
    auto hwrite = [&](float s0, float s1, float s2, float s3, int e0, int kc) {
        uint2 p01 = split_pk(s0, s1);
        uint2 p23 = split_pk(s2, s3);
        B2[(e0 + 0) * 136 + kc] = (u16)p01.x;
        B2[(e0 + 1) * 136 + kc] = (u16)(p01.x >> 16);
        B2[(e0 + 2) * 136 + kc] = (u16)p23.x;
        B2[(e0 + 3) * 136 + kc] = (u16)(p23.x >> 16);
        B2[(e0 + 0) * 136 + 64 + kc] = (u16)p01.y;
        B2[(e0 + 1) * 136 + 64 + kc] = (u16)(p01.y >> 16);
        B2[(e0 + 2) * 136 + 64 + kc] = (u16)p23.y;
        B2[(e0 + 3) * 136 + 64 + kc] = (u16)(p23.y >> 16);
    };

    // ---- P4: FC0 = fw @ w0; 24 MFMA; h0 -> B2
    f32x4 aF[2] = {};
    {
        const u16* bp = Wg + 65536 + (cw * 8) * 512 + l * 8;
        const u16* a0p = B1 + lm * 272 + lk8;
        const u16* a1p = B1 + (16 + lm) * 272 + lk8;
        __builtin_amdgcn_s_setprio(1);
        #pragma unroll 1
        for (int pass = 0; pass < 3; ++pass) {
            const int ao  = (pass == 1) ? 128 : 0;
            const int kb0 = (pass == 2) ? 4 : 0;
            #pragma unroll
            for (int ks = 0; ks < 4; ++ks) {
                bf16x8 a0 = *(const bf16x8*)(a0p + ao + 32 * ks);
                bf16x8 a1 = *(const bf16x8*)(a1p + ao + 32 * ks);
                bf16x8 b = *(const bf16x8*)(bp + (kb0 + ks) * 512);
                aF[0] = MFMA16(a0, b, aF[0]);
                aF[1] = MFMA16(a1, b, aF[1]);
            }
        }
        __builtin_amdgcn_s_setprio(0);
    }
    {
        float bb = fc_b0[16 * cw + lm];
        int kc = 16 * cw + lm;
        #pragma unroll
        for (int m = 0; m < 2; ++m) {
            float s[4];
            #pragma unroll
            for (int r = 0; r < 4; ++r) {
                float z = aF[m][r] + bb;
                s[r] = z * sigmoidf_(z);
            }
            hwrite(s[0], s[1], s[2], s[3], 16 * m + 4 * lk, kc);
        }
    }
    __syncthreads();                          // h0 ready; fw reads done

    // ---- P5: FC1 (regs only) || stage xv-i0 -> buf0 (B1 free)
    f32x4 aH[2] = {};
    {
        const u16* bp = Wg + 81920 + (cw * 4) * 512 + l * 8;
        const u16* a0p = B2 + lm * 136 + lk8;
        const u16* a1p = B2 + (16 + lm) * 136 + lk8;
        __builtin_amdgcn_s_setprio(1);
        #pragma unroll 1
        for (int pass = 0; pass < 3; ++pass) {
            const int ao  = (pass == 1) ? 64 : 0;
            const int kb0 = (pass == 2) ? 2 : 0;
            #pragma unroll
            for (int ks = 0; ks < 2; ++ks) {
                bf16x8 a0 = *(const bf16x8*)(a0p + ao + 32 * ks);
                bf16x8 a1 = *(const bf16x8*)(a1p + ao + 32 * ks);
                bf16x8 b = *(const bf16x8*)(bp + (kb0 + ks) * 512);
                aH[0] = MFMA16(a0, b, aH[0]);
                aH[1] = MFMA16(a1, b, aH[1]);
            }
        }
        __builtin_amdgcn_s_setprio(0);
    }
    stage_xv(0, B1);
    __syncthreads();                          // h0 reads done; i0 staged

    // ---- P6: h1 -> B2 || stage xv-i1 -> buf1
    {
        float bb = fc_b1[16 * cw + lm];
        int kc = 16 * cw + lm;
        #pragma unroll
        for (int m = 0; m < 2; ++m) {
            float s[4];
            #pragma unroll
            for (int r = 0; r < 4; ++r) {
                float z = aH[m][r] + bb;
                s[r] = z * sigmoidf_(z);
            }
            hwrite(s[0], s[1], s[2], s[3], 16 * m + 4 * lk, kc);
        }
    }
    stage_xv(1, B1 + 4352);
    __syncthreads();                          // h1 ready; i1 staged

    // ---- P7: FC2 = h1 @ w2 -> Wout (scal 2 tiles + gate 1); 36 MFMA
    f32x4 aW[3][2] = {};
    {
        const int ctn[3] = {2 * cw, 2 * cw + 1, 8 + cw};
        const u16* bp[3];
        #pragma unroll
        for (int c = 0; c < 3; ++c) bp[c] = Wg + 90112 + (ctn[c] * 4) * 512 + l * 8;
        const u16* a0p = B2 + lm * 136 + lk8;
        const u16* a1p = B2 + (16 + lm) * 136 + lk8;
        __builtin_amdgcn_s_setprio(1);
        #pragma unroll 1
        for (int pass = 0; pass < 3; ++pass) {
            const int ao  = (pass == 1) ? 64 : 0;
            const int kb0 = (pass == 2) ? 2 : 0;
            #pragma unroll
            for (int ks = 0; ks < 2; ++ks) {
                bf16x8 a0 = *(const bf16x8*)(a0p + ao + 32 * ks);
                bf16x8 a1 = *(const bf16x8*)(a1p + ao + 32 * ks);
                #pragma unroll
                for (int c = 0; c < 3; ++c) {
                    bf16x8 b = *(const bf16x8*)(bp[c] + (kb0 + ks) * 512);
                    aW[c][0] = MFMA16(a0, b, aW[c][0]);
                    aW[c][1] = MFMA16(a1, b, aW[c][1]);
                }
            }
        }
        __builtin_amdgcn_s_setprio(0);
        float b0v = fc_b2[32 * cw + lm];
        float b1v = fc_b2[32 * cw + 16 + lm];
        float bgv = fc_b2[128 + 16 * cw + lm];
        #pragma unroll
        for (int m = 0; m < 2; ++m)
            #pragma unroll
            for (int r = 0; r < 4; ++r) {
                aW[0][m][r] += b0v;
                aW[1][m][r] += b1v;
                aW[2][m][r] += bgv;
            }
    }
    __syncthreads();                          // h1 reads done

    // ---- P8: split-write d -> B2 (overwrites h1)
    {
        int de = t & 31, u0 = 8 * (t >> 5);
        unsigned dh[4], dl[4];
        #pragma unroll
        for (int q = 0; q < 4; ++q) {
            uint2 p = split_pk(d8[2 * q], d8[2 * q + 1]);
            dh[q] = p.x; dl[q] = p.y;
        }
        *(uint4*)&B2[de * 136 + u0]      = make_uint4(dh[0], dh[1], dh[2], dh[3]);
        *(uint4*)&B2[de * 136 + 64 + u0] = make_uint4(dl[0], dl[1], dl[2], dl[3]);
    }
    __syncthreads();                          // d ready

    // ---- P9: S2 = d @ Wd accumulated into aS1; scal epilogue; gates
    {
        const int ctn[3] = {2 * cw, 2 * cw + 1, 8 + cw};
        const u16* bp[3];
        #pragma unroll
        for (int c = 0; c < 3; ++c) bp[c] = Wg + 122880 + (ctn[c] * 4) * 512 + l * 8;
        const u16* a0p = B2 + lm * 136 + lk8;
        const u16* a1p = B2 + (16 + lm) * 136 + lk8;
        __builtin_amdgcn_s_setprio(1);
        #pragma unroll 1
        for (int pass = 0; pass < 3; ++pass) {
            const int ao  = (pass == 1) ? 64 : 0;
            const int kb0 = (pass == 2) ? 2 : 0;
            #pragma unroll
            for (int ks = 0; ks < 2; ++ks) {
                bf16x8 a0 = *(const bf16x8*)(a0p + ao + 32 * ks);
                bf16x8 a1 = *(const bf16x8*)(a1p + ao + 32 * ks);
                #pragma unroll
                for (int c = 0; c < 3; ++c) {
                    bf16x8 b = *(const bf16x8*)(bp[c] + (kb0 + ks) * 512);
                    aS1[c][0] = MFMA16(a0, b, aS1[c][0]);
                    aS1[c][1] = MFMA16(a1, b, aS1[c][1]);
                }
            }
        }
        __builtin_amdgcn_s_setprio(0);
    }
    // scal outputs: 64B-sector-aligned direct stores
    #pragma unroll
    for (int c2 = 0; c2 < 2; ++c2)
        #pragma unroll
        for (int m = 0; m < 2; ++m)
            #pragma unroll
            for (int r = 0; r < 4; ++r) {
                float s = aS1[c2][m][r];
                int e = 16 * m + 4 * lk + r;
                out[(e0b + e) * 320 + 32 * cw + 16 * c2 + lm] =
                    s * sigmoidf_(s) * aW[c2][m][r];
            }
    float G[2][4];
    #pragma unroll
    for (int m = 0; m < 2; ++m)
        #pragma unroll
        for (int r = 0; r < 4; ++r)
            G[m][r] = sigmoidf_(aS1[2][m][r]) * aW[2][m][r];

    // per-i A3 GEMM; results accumulated into vo regs
    float vo[3][2][4];
    auto vec_phase = [&](int i, const u16* buf) {
        f32x4 aA[2] = {};
        const u16* bp = Wg + 114688 + (cw * 4) * 512 + l * 8;
        const u16* a0p = buf + lm * 136 + lk8;
        const u16* a1p = buf + (16 + lm) * 136 + lk8;
        __builtin_amdgcn_s_setprio(1);
        #pragma unroll 1
        for (int pass = 0; pass < 3; ++pass) {
            const int ao  = (pass == 1) ? 64 : 0;
            const int kb0 = (pass == 2) ? 2 : 0;
            #pragma unroll
            for (int ks = 0; ks < 2; ++ks) {
                bf16x8 a0 = *(const bf16x8*)(a0p + ao + 32 * ks);
                bf16x8 a1 = *(const bf16x8*)(a1p + ao + 32 * ks);
                bf16x8 b = *(const bf16x8*)(bp + (kb0 + ks) * 512);
                aA[0] = MFMA16(a0, b, aA[0]);
                aA[1] = MFMA16(a1, b, aA[1]);
            }
        }
        __builtin_amdgcn_s_setprio(0);
        #pragma unroll
        for (int m = 0; m < 2; ++m)
            #pragma unroll
            for (int r = 0; r < 4; ++r) {
                int e = 16 * m + 4 * lk + r;
                vo[i][m][r] = G[m][r] * (aS1[3][m][r] * X2[32 * (1 + i) + e]
                                         + aA[m][r] * X2[e]);
            }
    };

    // ---- P10..P12: A3-i0 | A3-i1 || stage-i2 | A3-i2
    vec_phase(0, B1);                         // buf0 staged at P5
    __syncthreads();                          // buf0 reads done
    vec_phase(1, B1 + 4352);
    stage_xv(2, B1);
    __syncthreads();                          // i2 staged; buf1 reads done
    vec_phase(2, B1);

    // ---- P13: bounce vec outputs through LDS -> coalesced float4 stores
    __syncthreads();                          // all LDS reads done (OB aliases B1/B2)
    #pragma unroll
    for (int i = 0; i < 3; ++i)
        #pragma unroll
        for (int m = 0; m < 2; ++m)
            #pragma unroll
            for (int r = 0; r < 4; ++r) {
                int e = 16 * m + 4 * lk + r;
                OB[e * 196 + 3 * (16 * cw + lm) + i] = vo[i][m][r];
            }
    __syncthreads();
    #pragma unroll
    for (int r6 = 0; r6 < 6; ++r6) {
        int f = t + r6 * 256;                 // 1536 float4 = 32 x 192
        int row = f / 48, c4 = f - row * 48;
        float4 v = *(const float4*)&OB[row * 196 + c4 * 4];
        *(float4*)(out + (e0b + row) * 320 + 128 + c4 * 4) = v;
    }
}

// ---------------------------------------------------------------- launch
extern "C" void kernel_launch(void* const* d_in, const int* in_sizes, int n_in,
                              void* d_out, int out_size, void* d_ws, size_t ws_size,
                              hipStream_t stream) {
    const float* fea_in1 = (const float*)d_in[0];
    const float* fea_in2 = (const float*)d_in[1];
    const float* fea_w   = (const float*)d_in[2];
    // d_in[3] = batch_edge (unused by reference)
    const float* w1_p0 = (const float*)d_in[4];
    const float* w2_p0 = (const float*)d_in[5];
    const float* w1_p1 = (const float*)d_in[6];
    const float* w2_p1 = (const float*)d_in[7];
    const float* w1_p2 = (const float*)d_in[8];
    const float* w2_p2 = (const float*)d_in[9];
    const float* w1_p3 = (const float*)d_in[10];
    const float* w2_p3 = (const float*)d_in[11];
    const float* w1_p4 = (const float*)d_in[12];
    const float* w2_p4 = (const float*)d_in[13];
    const float* w1_p5 = (const float*)d_in[14];
    const float* w2_p5 = (const float*)d_in[15];
    const float* fc_w0 = (const float*)d_in[16];
    const float* fc_b0 = (const float*)d_in[17];
    const float* fc_w1 = (const float*)d_in[18];
    const float* fc_b1 = (const float*)d_in[19];
    const float* fc_w2 = (const float*)d_in[20];
    const float* fc_b2 = (const float*)d_in[21];

    const int E = in_sizes[0] / 320;   // 200000

    u16* W = (u16*)d_ws;               // 147456 u16 = 288 KB
    float* out = (float*)d_out;

    prep_weights<<<576, 256, 0, stream>>>(w1_p0, w2_p0, w1_p1, w2_p1, w1_p2, w2_p2,
                                          w1_p3, w2_p3, w1_p4, w2_p4, w1_p5, w2_p5,
                                          fc_w0, fc_w1, fc_w2, W);
    fused_kernel<<<E / 32, 256, 0, stream>>>(fea_in1, fea_in2, fea_w,
                                             fc_b0, fc_b1, fc_b2, W, out);
}

// Round 10
// 633.903 us; speedup vs baseline: 1.0754x; 1.0754x over previous
//
#include <hip/hip_runtime.h>

// EquiConv fully-fused pipeline (round 11): MFMA split-bf16, conflict-free pitches.
// E = 200000, MUL_S = 128, MUL_V = 64, FC_IN = 128, FC_HID = 64, LEN_W = 192.
//
// Base = round 8 (310 us verified; manual f2bf splits -- round 9's inline-asm
// cvt_pk regressed 9%, per guide T12/m240). Changes:
//   1. LDS pitches fixed for ds_read_b128 bank behavior (G4):
//      B1 272->280 u16 (136->140 dwords, %32: 8->12 => 4-way -> 2-way free),
//      B2/xv/D 136->152 u16 (68->76 dwords, %32: 4->12 => 2-way). All pitches
//      remain x8 u16 so 16B alignment of b128 ops holds.
//   2. d[e][u] split-written to a dedicated D region at P3 (was held in 8
//      regs until P8): kills phase P8 + 2 barriers, frees 8 regs across the
//      fattest live range (P4-P7). LDS 39.4KB/block, still 4 blocks/CU.
//   3. s_setprio(1) around MFMA clusters (T5; retested on good base).
//
// MFMA layouts (gfx950, verified rounds 6-9):
//   A-frag: lane holds A[row = l&15][k = 32*ks + 8*(l>>4) + j]
//   B-frag: lane holds B[k][col = l&15] from fragment-ordered storage
//   C/D  : col = l&15, row = 4*(l>>4) + reg
//
// LDS (u16 offsets): B1 0 (9728: x1s/fw [32][280]; later 2 xv bufs [32][152])
//   B2 9728 (4864: h0/h1 [32][152]) | D 14592 (4864: d [32][152])
//   X2 19456 (256: [4][32] f32) | OB aliases bytes [0,25088) for the bounce.
//
// ws (u16): WB 0 (65536) | W0 65536 (16384) | W1 81920 (8192)
//           W2 90112 (24576) | WP3 114688 (8192) | WD 122880 (24576)

typedef short bf16x8 __attribute__((ext_vector_type(8)));
typedef float f32x4 __attribute__((ext_vector_type(4)));
typedef unsigned short u16;
typedef unsigned short u16x4 __attribute__((ext_vector_type(4)));

#define MFMA16(a, b, c) __builtin_amdgcn_mfma_f32_16x16x32_bf16((a), (b), (c), 0, 0, 0)

__device__ __forceinline__ u16 f2bf(float x) {
    unsigned u = __float_as_uint(x);
    u += 0x7FFFu + ((u >> 16) & 1u);
    return (u16)(u >> 16);
}
__device__ __forceinline__ float bf2f(u16 h) {
    return __uint_as_float(((unsigned)h) << 16);
}
__device__ __forceinline__ float sigmoidf_(float x) { return 1.0f / (1.0f + __expf(-x)); }

__device__ __forceinline__ void split_wr(u16* hip, u16* lop, float4 v) {
    u16x4 h, lo;
    h.x = f2bf(v.x); h.y = f2bf(v.y); h.z = f2bf(v.z); h.w = f2bf(v.w);
    lo.x = f2bf(v.x - bf2f(h.x)); lo.y = f2bf(v.y - bf2f(h.y));
    lo.z = f2bf(v.z - bf2f(h.z)); lo.w = f2bf(v.w - bf2f(h.w));
    *(u16x4*)hip = h;
    *(u16x4*)lop = lo;
}

// ---------------------------------------------------------------- prep
// Fragment-ordered split weights: flat = ((nt*KB2 + kb)*64 + lane)*8 + j;
// n = 16*nt + (lane&15); k = 32*(kb mod KS) + 8*(lane>>4) + j; kb<KS -> hi.
__global__ __launch_bounds__(256) void prep_weights(
    const float* __restrict__ w1_p0, const float* __restrict__ w2_p0,
    const float* __restrict__ w1_p1, const float* __restrict__ w2_p1,
    const float* __restrict__ w1_p2, const float* __restrict__ w2_p2,
    const float* __restrict__ w1_p3, const float* __restrict__ w2_p3,
    const float* __restrict__ w1_p4, const float* __restrict__ w2_p4,
    const float* __restrict__ w1_p5, const float* __restrict__ w2_p5,
    const float* __restrict__ fc_w0, const float* __restrict__ fc_w1,
    const float* __restrict__ fc_w2,
    u16* __restrict__ W)
{
    const float INV_S = 0.08838834764831845f;   // 1/sqrt(128)
    const float INV_V = 0.125f;                 // 1/sqrt(64)
    const float SQ2   = 0.7071067811865476f;
    const float SQ3   = 0.5773502691896258f;
    int gid = blockIdx.x * 256 + threadIdx.x;
    if (gid >= 147456) return;
    float w = 0.f;
    int islo = 0;
    if (gid < 65536) {                       // WB: N=256 K=128 (Wbig)
        int g = gid, j = g & 7, ll = (g >> 3) & 63, rest = g >> 9;
        int kb = rest & 7, nt = rest >> 3;
        int n = nt * 16 + (ll & 15);
        islo = (kb >= 4);
        int k = 32 * (kb & 3) + 8 * (ll >> 4) + j;
        if (n < 128)      w = w1_p0[k * 128 + n] * w2_p0[n];
        else if (n < 192) w = w1_p1[k * 64 + (n - 128)] * w2_p1[n - 128];
        else              w = w1_p2[k * 64 + (n - 192)] * w2_p2[n - 192];
        w *= (INV_S * SQ2);
    } else if (gid < 81920) {                // W0: N=64 K=128
        int g = gid - 65536, j = g & 7, ll = (g >> 3) & 63, rest = g >> 9;
        int kb = rest & 7, nt = rest >> 3;
        int n = nt * 16 + (ll & 15);
        islo = (kb >= 4);
        int k = 32 * (kb & 3) + 8 * (ll >> 4) + j;
        w = fc_w0[k * 64 + n];
    } else if (gid < 90112) {                // W1: N=64 K=64
        int g = gid - 81920, j = g & 7, ll = (g >> 3) & 63, rest = g >> 9;
        int kb = rest & 3, nt = rest >> 2;
        int n = nt * 16 + (ll & 15);
        islo = (kb >= 2);
        int k = 32 * (kb & 1) + 8 * (ll >> 4) + j;
        w = fc_w1[k * 64 + n];
    } else if (gid < 114688) {               // W2: N=192 K=64
        int g = gid - 90112, j = g & 7, ll = (g >> 3) & 63, rest = g >> 9;
        int kb = rest & 3, nt = rest >> 2;
        int n = nt * 16 + (ll & 15);
        islo = (kb >= 2);
        int k = 32 * (kb & 1) + 8 * (ll >> 4) + j;
        w = fc_w2[k * 192 + n];
    } else if (gid < 122880) {               // WP3: N=64(w) K=64(u), w1_p3 scaled
        int g = gid - 114688, j = g & 7, ll = (g >> 3) & 63, rest = g >> 9;
        int kb = rest & 3, nt = rest >> 2;
        int n = nt * 16 + (ll & 15);
        islo = (kb >= 2);
        int k = 32 * (kb & 1) + 8 * (ll >> 4) + j;
        w = w1_p3[k * 64 + n] * w2_p3[n] * (INV_V * SQ2);
    } else {                                 // WD: N=192 K=64 (Wd)
        int g = gid - 122880, j = g & 7, ll = (g >> 3) & 63, rest = g >> 9;
        int kb = rest & 3, nt = rest >> 2;
        int n = nt * 16 + (ll & 15);
        islo = (kb >= 2);
        int k = 32 * (kb & 1) + 8 * (ll >> 4) + j;
        w = (n < 128 ? w1_p4[k * 128 + n] * w2_p4[n]
                     : w1_p5[k * 64 + (n - 128)] * w2_p5[n - 128]) * (INV_V * SQ3 * SQ2);
    }
    u16 h = f2bf(w);
    W[gid] = islo ? f2bf(w - bf2f(h)) : h;
}

// ---------------------------------------------------------------- fused
__global__ __launch_bounds__(256, 4) void fused_kernel(
    const float* __restrict__ fea_in1, const float* __restrict__ fea_in2,
    const float* __restrict__ fea_w,
    const float* __restrict__ fc_b0, const float* __restrict__ fc_b1,
    const float* __restrict__ fc_b2,
    const u16* __restrict__ Wg,
    float* __restrict__ out)
{
    __shared__ __align__(16) u16 SM[19712];      // 39424 B
    u16* B1 = SM;                 // x1s/fw [32][280]; later xv bufs 2x[32][152]
    u16* B2 = SM + 9728;          // h0/h1 [32][152]
    u16* DD = SM + 14592;         // d [32][152]
    float* X2 = (float*)(SM + 19456);  // [4][32] f32
    float* OB = (float*)SM;       // vec-out bounce [32][196] f32 (25088 B)

    const int t   = threadIdx.x;
    const int l   = t & 63;
    const int cw  = t >> 6;       // wave id 0..3 (column wave)
    const int lm  = l & 15;
    const int lk  = l >> 4;
    const int lk8 = lk * 8;
    const long e0b = (long)blockIdx.x * 32;

    // ---- P1: stage x2 (transposed) + split x1s (pitch 280)
    if (t < 32) {
        float4 v = *(const float4*)(fea_in2 + (e0b + t) * 4);
        X2[t] = v.x; X2[32 + t] = v.y; X2[64 + t] = v.z; X2[96 + t] = v.w;
    }
    #pragma unroll
    for (int r = 0; r < 4; ++r) {
        int f = t + r * 256, ee = f >> 5, c4 = f & 31;
        float4 v = *(const float4*)(fea_in1 + (e0b + ee) * 320 + c4 * 4);
        split_wr(&B1[ee * 280 + c4 * 4], &B1[ee * 280 + 128 + c4 * 4], v);
    }
    __syncthreads();

    // ---- P2: S1 = x1s @ Wbig -> scal(2 tiles) gate(1) vcoef(1); 96 MFMA
    f32x4 aS1[4][2] = {};
    {
        const int ctn[4] = {2 * cw, 2 * cw + 1, 8 + cw, 12 + cw};
        const u16* bp[4];
        #pragma unroll
        for (int c = 0; c < 4; ++c) bp[c] = Wg + (ctn[c] * 8) * 512 + l * 8;
        const u16* a0p = B1 + lm * 280 + lk8;
        const u16* a1p = B1 + (16 + lm) * 280 + lk8;
        __builtin_amdgcn_s_setprio(1);
        #pragma unroll 1
        for (int pass = 0; pass < 3; ++pass) {
            const int ao  = (pass == 1) ? 128 : 0;
            const int kb0 = (pass == 2) ? 4 : 0;
            #pragma unroll
            for (int ks = 0; ks < 4; ++ks) {
                bf16x8 a0 = *(const bf16x8*)(a0p + ao + 32 * ks);
                bf16x8 a1 = *(const bf16x8*)(a1p + ao + 32 * ks);
                #pragma unroll
                for (int c = 0; c < 4; ++c) {
                    bf16x8 b = *(const bf16x8*)(bp[c] + (kb0 + ks) * 512);
                    aS1[c][0] = MFMA16(a0, b, aS1[c][0]);
                    aS1[c][1] = MFMA16(a1, b, aS1[c][1]);
                }
            }
        }
        __builtin_amdgcn_s_setprio(0);
    }
    // fold x2s into scal+gate tiles (NOT vcoef)
    #pragma unroll
    for (int m = 0; m < 2; ++m)
        #pragma unroll
        for (int r = 0; r < 4; ++r) {
            float xs = X2[16 * m + 4 * lk + r];
            aS1[0][m][r] *= xs;
            aS1[1][m][r] *= xs;
            aS1[2][m][r] *= xs;
        }
    __syncthreads();                          // x1s reads done

    // ---- P3: stage fw over B1; d[e][u] from fp32 global xv -> split into DD
    #pragma unroll
    for (int r = 0; r < 4; ++r) {
        int f = t + r * 256, ee = f >> 5, c4 = f & 31;
        float4 v = *(const float4*)(fea_w + (e0b + ee) * 128 + c4 * 4);
        split_wr(&B1[ee * 280 + c4 * 4], &B1[ee * 280 + 128 + c4 * 4], v);
    }
    {
        int de = t & 31, u0 = 8 * (t >> 5);
        const float* p = fea_in1 + (e0b + de) * 320 + 128 + 3 * u0;
        float4 qa = *(const float4*)(p +  0), qb = *(const float4*)(p +  4);
        float4 qc = *(const float4*)(p +  8), qd = *(const float4*)(p + 12);
        float4 qe = *(const float4*)(p + 16), qf = *(const float4*)(p + 20);
        float c1 = X2[32 + de], c2 = X2[64 + de], c3 = X2[96 + de];
        float d8[8];
        d8[0] = qa.x * c1 + qa.y * c2 + qa.z * c3;
        d8[1] = qa.w * c1 + qb.x * c2 + qb.y * c3;
        d8[2] = qb.z * c1 + qb.w * c2 + qc.x * c3;
        d8[3] = qc.y * c1 + qc.z * c2 + qc.w * c3;
        d8[4] = qd.x * c1 + qd.y * c2 + qd.z * c3;
        d8[5] = qd.w * c1 + qe.x * c2 + qe.y * c3;
        d8[6] = qe.z * c1 + qe.w * c2 + qf.x * c3;
        d8[7] = qf.y * c1 + qf.z * c2 + qf.w * c3;
        bf16x8 hv, lv;
        #pragma unroll
        for (int q = 0; q < 8; ++q) {
            u16 h = f2bf(d8[q]);
            hv[q] = (short)h;
            lv[q] = (short)f2bf(d8[q] - bf2f(h));
        }
        *(bf16x8*)&DD[de * 152 + u0]      = hv;
        *(bf16x8*)&DD[de * 152 + 64 + u0] = lv;
    }
    __syncthreads();

    // xv i-tile stager: 32 rows x 64 u, stride-12B gather (L1/L2-hot after P3)
    auto stage_xv = [&](int i, u16* buf) {
        int ee = t >> 3, u0 = 8 * (t & 7);
        const float* p = fea_in1 + (e0b + ee) * 320 + 128 + i + 3 * u0;
        bf16x8 hv, lv;
        #pragma unroll
        for (int q = 0; q < 8; ++q) {
            float v = p[3 * q];
            u16 h = f2bf(v);
            hv[q] = (short)h;
            lv[q] = (short)f2bf(v - bf2f(h));
        }
        *(bf16x8*)&buf[ee * 152 + u0]      = hv;
        *(bf16x8*)&buf[ee * 152 + 64 + u0] = lv;
    };

    // ---- P4: FC0 = fw @ w0; 24 MFMA; h0 -> B2
    f32x4 aF[2] = {};
    {
        const u16* bp = Wg + 65536 + (cw * 8) * 512 + l * 8;
        const u16* a0p = B1 + lm * 280 + lk8;
        const u16* a1p = B1 + (16 + lm) * 280 + lk8;
        __builtin_amdgcn_s_setprio(1);
        #pragma unroll 1
        for (int pass = 0; pass < 3; ++pass) {
            const int ao  = (pass == 1) ? 128 : 0;
            const int kb0 = (pass == 2) ? 4 : 0;
            #pragma unroll
            for (int ks = 0; ks < 4; ++ks) {
                bf16x8 a0 = *(const bf16x8*)(a0p + ao + 32 * ks);
                bf16x8 a1 = *(const bf16x8*)(a1p + ao + 32 * ks);
                bf16x8 b = *(const bf16x8*)(bp + (kb0 + ks) * 512);
                aF[0] = MFMA16(a0, b, aF[0]);
                aF[1] = MFMA16(a1, b, aF[1]);
            }
        }
        __builtin_amdgcn_s_setprio(0);
    }
    {
        float bb = fc_b0[16 * cw + lm];
        #pragma unroll
        for (int m = 0; m < 2; ++m)
            #pragma unroll
            for (int r = 0; r < 4; ++r) {
                float z = aF[m][r] + bb;
                float s = z * sigmoidf_(z);
                int e = 16 * m + 4 * lk + r;
                u16 hh = f2bf(s);
                B2[e * 152 + 16 * cw + lm] = hh;
                B2[e * 152 + 64 + 16 * cw + lm] = f2bf(s - bf2f(hh));
            }
    }
    __syncthreads();                          // h0 ready; fw reads done

    // ---- P5: FC1 (regs only) || stage xv-i0 -> buf0 (B1 free)
    f32x4 aH[2] = {};
    {
        const u16* bp = Wg + 81920 + (cw * 4) * 512 + l * 8;
        const u16* a0p = B2 + lm * 152 + lk8;
        const u16* a1p = B2 + (16 + lm) * 152 + lk8;
        __builtin_amdgcn_s_setprio(1);
        #pragma unroll 1
        for (int pass = 0; pass < 3; ++pass) {
            const int ao  = (pass == 1) ? 64 : 0;
            const int kb0 = (pass == 2) ? 2 : 0;
            #pragma unroll
            for (int ks = 0; ks < 2; ++ks) {
                bf16x8 a0 = *(const bf16x8*)(a0p + ao + 32 * ks);
                bf16x8 a1 = *(const bf16x8*)(a1p + ao + 32 * ks);
                bf16x8 b = *(const bf16x8*)(bp + (kb0 + ks) * 512);
                aH[0] = MFMA16(a0, b, aH[0]);
                aH[1] = MFMA16(a1, b, aH[1]);
            }
        }
        __builtin_amdgcn_s_setprio(0);
    }
    stage_xv(0, B1);
    __syncthreads();                          // h0 reads done; i0 staged

    // ---- P6: h1 -> B2 (over h0) || stage xv-i1 -> buf1
    {
        float bb = fc_b1[16 * cw + lm];
        #pragma unroll
        for (int m = 0; m < 2; ++m)
            #pragma unroll
            for (int r = 0; r < 4; ++r) {
                float z = aH[m][r] + bb;
                float s = z * sigmoidf_(z);
                int e = 16 * m + 4 * lk + r;
                u16 hh = f2bf(s);
                B2[e * 152 + 16 * cw + lm] = hh;
                B2[e * 152 + 64 + 16 * cw + lm] = f2bf(s - bf2f(hh));
            }
    }
    stage_xv(1, B1 + 4864);
    __syncthreads();                          // h1 ready; i1 staged

    // ---- P7: FC2 = h1 @ w2 -> Wout (scal 2 tiles + gate 1); 36 MFMA
    f32x4 aW[3][2] = {};
    {
        const int ctn[3] = {2 * cw, 2 * cw + 1, 8 + cw};
        const u16* bp[3];
        #pragma unroll
        for (int c = 0; c < 3; ++c) bp[c] = Wg + 90112 + (ctn[c] * 4) * 512 + l * 8;
        const u16* a0p = B2 + lm * 152 + lk8;
        const u16* a1p = B2 + (16 + lm) * 152 + lk8;
        __builtin_amdgcn_s_setprio(1);
        #pragma unroll 1
        for (int pass = 0; pass < 3; ++pass) {
            const int ao  = (pass == 1) ? 64 : 0;
            const int kb0 = (pass == 2) ? 2 : 0;
            #pragma unroll
            for (int ks = 0; ks < 2; ++ks) {
                bf16x8 a0 = *(const bf16x8*)(a0p + ao + 32 * ks);
                bf16x8 a1 = *(const bf16x8*)(a1p + ao + 32 * ks);
                #pragma unroll
                for (int c = 0; c < 3; ++c) {
                    bf16x8 b = *(const bf16x8*)(bp[c] + (kb0 + ks) * 512);
                    aW[c][0] = MFMA16(a0, b, aW[c][0]);
                    aW[c][1] = MFMA16(a1, b, aW[c][1]);
                }
            }
        }
        __builtin_amdgcn_s_setprio(0);
        float b0v = fc_b2[32 * cw + lm];
        float b1v = fc_b2[32 * cw + 16 + lm];
        float bgv = fc_b2[128 + 16 * cw + lm];
        #pragma unroll
        for (int m = 0; m < 2; ++m)
            #pragma unroll
            for (int r = 0; r < 4; ++r) {
                aW[0][m][r] += b0v;
                aW[1][m][r] += b1v;
                aW[2][m][r] += bgv;
            }
    }
    // no barrier: nothing overwrites B2; S2 reads DD (written P3)

    // ---- P9: S2 = d @ Wd accumulated into aS1; scal epilogue; gates
    {
        const int ctn[3] = {2 * cw, 2 * cw + 1, 8 + cw};
        const u16* bp[3];
        #pragma unroll
        for (int c = 0; c < 3; ++c) bp[c] = Wg + 122880 + (ctn[c] * 4) * 512 + l * 8;
        const u16* a0p = DD + lm * 152 + lk8;
        const u16* a1p = DD + (16 + lm) * 152 + lk8;
        __builtin_amdgcn_s_setprio(1);
        #pragma unroll 1
        for (int pass = 0; pass < 3; ++pass) {
            const int ao  = (pass == 1) ? 64 : 0;
            const int kb0 = (pass == 2) ? 2 : 0;
            #pragma unroll
            for (int ks = 0; ks < 2; ++ks) {
                bf16x8 a0 = *(const bf16x8*)(a0p + ao + 32 * ks);
                bf16x8 a1 = *(const bf16x8*)(a1p + ao + 32 * ks);
                #pragma unroll
                for (int c = 0; c < 3; ++c) {
                    bf16x8 b = *(const bf16x8*)(bp[c] + (kb0 + ks) * 512);
                    aS1[c][0] = MFMA16(a0, b, aS1[c][0]);
                    aS1[c][1] = MFMA16(a1, b, aS1[c][1]);
                }
            }
        }
        __builtin_amdgcn_s_setprio(0);
    }
    // scal outputs: 64B-sector-aligned direct stores
    #pragma unroll
    for (int c2 = 0; c2 < 2; ++c2)
        #pragma unroll
        for (int m = 0; m < 2; ++m)
            #pragma unroll
            for (int r = 0; r < 4; ++r) {
                float s = aS1[c2][m][r];
                int e = 16 * m + 4 * lk + r;
                out[(e0b + e) * 320 + 32 * cw + 16 * c2 + lm] =
                    s * sigmoidf_(s) * aW[c2][m][r];
            }
    float G[2][4];
    #pragma unroll
    for (int m = 0; m < 2; ++m)
        #pragma unroll
        for (int r = 0; r < 4; ++r)
            G[m][r] = sigmoidf_(aS1[2][m][r]) * aW[2][m][r];

    // per-i A3 GEMM; results accumulated into vo regs
    float vo[3][2][4];
    auto vec_phase = [&](int i, const u16* buf) {
        f32x4 aA[2] = {};
        const u16* bp = Wg + 114688 + (cw * 4) * 512 + l * 8;
        const u16* a0p = buf + lm * 152 + lk8;
        const u16* a1p = buf + (16 + lm) * 152 + lk8;
        __builtin_amdgcn_s_setprio(1);
        #pragma unroll 1
        for (int pass = 0; pass < 3; ++pass) {
            const int ao  = (pass == 1) ? 64 : 0;
            const int kb0 = (pass == 2) ? 2 : 0;
            #pragma unroll
            for (int ks = 0; ks < 2; ++ks) {
                bf16x8 a0 = *(const bf16x8*)(a0p + ao + 32 * ks);
                bf16x8 a1 = *(const bf16x8*)(a1p + ao + 32 * ks);
                bf16x8 b = *(const bf16x8*)(bp + (kb0 + ks) * 512);
                aA[0] = MFMA16(a0, b, aA[0]);
                aA[1] = MFMA16(a1, b, aA[1]);
            }
        }
        __builtin_amdgcn_s_setprio(0);
        #pragma unroll
        for (int m = 0; m < 2; ++m)
            #pragma unroll
            for (int r = 0; r < 4; ++r) {
                int e = 16 * m + 4 * lk + r;
                vo[i][m][r] = G[m][r] * (aS1[3][m][r] * X2[32 * (1 + i) + e]
                                         + aA[m][r] * X2[e]);
            }
    };

    // ---- P10..P12: A3-i0 | A3-i1 || stage-i2 | A3-i2
    vec_phase(0, B1);                         // buf0 staged at P5
    __syncthreads();                          // buf0 reads done
    vec_phase(1, B1 + 4864);
    stage_xv(2, B1);
    __syncthreads();                          // i2 staged; buf1 reads done
    vec_phase(2, B1);

    // ---- P13: bounce vec outputs through LDS -> coalesced float4 stores
    __syncthreads();                          // all LDS reads done (OB aliases B1/B2)
    #pragma unroll
    for (int i = 0; i < 3; ++i)
        #pragma unroll
        for (int m = 0; m < 2; ++m)
            #pragma unroll
            for (int r = 0; r < 4; ++r) {
                int e = 16 * m + 4 * lk + r;
                OB[e * 196 + 3 * (16 * cw + lm) + i] = vo[i][m][r];
            }
    __syncthreads();
    #pragma unroll
    for (int r6 = 0; r6 < 6; ++r6) {
        int f = t + r6 * 256;                 // 1536 float4 = 32 x 192
        int row = f / 48, c4 = f - row * 48;
        float4 v = *(const float4*)&OB[row * 196 + c4 * 4];
        *(float4*)(out + (e0b + row) * 320 + 128 + c4 * 4) = v;
    }
}

// ---------------------------------------------------------------- launch
extern "C" void kernel_launch(void* const* d_in, const int* in_sizes, int n_in,
                              void* d_out, int out_size, void* d_ws, size_t ws_size,
                              hipStream_t stream) {
    const float* fea_in1 = (const float*)d_in[0];
    const float* fea_in2 = (const float*)d_in[1];
    const float* fea_w   = (const float*)d_in[2];
    // d_in[3] = batch_edge (unused by reference)
    const float* w1_p0 = (const float*)d_in[4];
    const float* w2_p0 = (const float*)d_in[5];
    const float* w1_p1 = (const float*)d_in[6];
    const float* w2_p1 = (const float*)d_in[7];
    const float* w1_p2 = (const float*)d_in[8];
    const float* w2_p2 = (const float*)d_in[9];
    const float* w1_p3 = (const float*)d_in[10];
    const float* w2_p3 = (const float*)d_in[11];
    const float* w1_p4 = (const float*)d_in[12];
    const float* w2_p4 = (const float*)d_in[13];
    const float* w1_p5 = (const float*)d_in[14];
    const float* w2_p5 = (const float*)d_in[15];
    const float* fc_w0 = (const float*)d_in[16];
    const float* fc_b0 = (const float*)d_in[17];
    const float* fc_w1 = (const float*)d_in[18];
    const float* fc_b1 = (const float*)d_in[19];
    const float* fc_w2 = (const float*)d_in[20];
    const float* fc_b2 = (const float*)d_in[21];

    const int E = in_sizes[0] / 320;   // 200000

    u16* W = (u16*)d_ws;               // 147456 u16 = 288 KB
    float* out = (float*)d_out;

    prep_weights<<<576, 256, 0, stream>>>(w1_p0, w2_p0, w1_p1, w2_p1, w1_p2, w2_p2,
                                          w1_p3, w2_p3, w1_p4, w2_p4, w1_p5, w2_p5,
                                          fc_w0, fc_w1, fc_w2, W);
    fused_kernel<<<E / 32, 256, 0, stream>>>(fea_in1, fea_in2, fea_w,
                                             fc_b0, fc_b1, fc_b2, W, out);
}